// Round 1
// baseline (341.467 us; speedup 1.0000x reference)
//
#include <hip/hip_runtime.h>
#include <hip/hip_bf16.h>

#define N_    2
#define T_    7
#define C_    96
#define H_    96
#define W_    96
#define HW_   9216
#define HEAD_ 4
#define HD_   24
#define C3_   288
#define P_    16           // pixels per block (was 32): grid 1152, LDS 26.6KB -> better occupancy
#define QP_   100          // padded stride for q/k tiles (mult of 4 -> 16B-aligned float4)
#define CATP_ 292          // padded stride for cat tile (mult of 4)
#define NBLK_ (N_ * (HW_ / P_))   // 1152
#define PLANES_ 14         // n*t
#define CHUNK_  64
#define NCHUNK_ 144        // 9216/64

typedef unsigned int u32;

__device__ __forceinline__ float bits2f(u32 b) {
    union { u32 u; float f; } x; x.u = b; return x.f;
}

__device__ __forceinline__ unsigned short f2bf(float f) {
    union { __hip_bfloat16 h; unsigned short s; } u;
    u.h = __float2bfloat16(f);
    return u.s;
}

template<bool BF16>
__device__ __forceinline__ float ld1(const void* p, int i) {
    if constexpr (BF16) return bits2f(((u32)((const unsigned short*)p)[i]) << 16);
    else                return ((const float*)p)[i];
}

// load 4 consecutive elements starting at i (i % 4 == 0)
template<bool BF16>
__device__ __forceinline__ void ld4w(const void* p, int i, float w[4]) {
    if constexpr (BF16) {
        const uint2 u = ((const uint2*)p)[i >> 2];
        w[0] = bits2f(u.x << 16);
        w[1] = bits2f(u.x & 0xFFFF0000u);
        w[2] = bits2f(u.y << 16);
        w[3] = bits2f(u.y & 0xFFFF0000u);
    } else {
        const float4 v = *((const float4*)((const float*)p + i));
        w[0] = v.x; w[1] = v.y; w[2] = v.z; w[3] = v.w;
    }
}

// store 4 consecutive elements starting at i (i % 4 == 0)
template<bool BF16>
__device__ __forceinline__ void st4w(void* p, int i, const float v[4]) {
    if constexpr (BF16) {
        uint2 w;
        w.x = (u32)f2bf(v[0]) | ((u32)f2bf(v[1]) << 16);
        w.y = (u32)f2bf(v[2]) | ((u32)f2bf(v[3]) << 16);
        ((uint2*)p)[i >> 2] = w;
    } else {
        *((float4*)((float*)p + i)) = make_float4(v[0], v[1], v[2], v[3]);
    }
}

// ---- dtype detector (unchanged from verified kernel) ----
__global__ void detect_dtype_kernel(const u32* __restrict__ w, int* __restrict__ flag) {
    u32 x = w[threadIdx.x];
    u32 f = x & 0x7FFFu;
    int inwin = (f >= 0x3A00u) && (f <= 0x4200u);
    unsigned long long m = __ballot(inwin);
    if (threadIdx.x == 0) flag[0] = (__popcll(m) >= 40) ? 1 : 0;
}

// ---- (c,hw) -> (hw,c) transpose per (n*t) plane, bit-exact copy.
// blockIdx.x = plane*NCHUNK_ + chunk; blockIdx.y = which array (0=idxf,1..3=s1..s3)
template<bool BF16>
__global__ __launch_bounds__(256) void transp_kernel(
    const void* __restrict__ a0, const void* __restrict__ a1,
    const void* __restrict__ a2, const void* __restrict__ a3,
    void* __restrict__ dstb, unsigned long long szb, const int* __restrict__ flag)
{
    if ((*flag != 0) != BF16) return;
    const int arr = blockIdx.y;
    const void* src = (arr == 0) ? a0 : (arr == 1) ? a1 : (arr == 2) ? a2 : a3;
    void* dst = (char*)dstb + (unsigned long long)arr * szb;
    const int bx = blockIdx.x;
    const int pl = bx / NCHUNK_;
    const int x0 = (bx - pl * NCHUNK_) * CHUNK_;
    const int tid = threadIdx.x;
    if constexpr (BF16) {
        __shared__ unsigned short tile[C_][CHUNK_ + 2];
        const unsigned short* s = (const unsigned short*)src;
        unsigned short* d = (unsigned short*)dst;
        for (int i = tid; i < C_ * (CHUNK_ / 4); i += 256) {
            int ch = i >> 4, xq = i & 15;
            const ushort4 v = *((const ushort4*)(s + (pl * C_ + ch) * HW_ + x0 + 4 * xq));
            tile[ch][4 * xq + 0] = v.x; tile[ch][4 * xq + 1] = v.y;
            tile[ch][4 * xq + 2] = v.z; tile[ch][4 * xq + 3] = v.w;
        }
        __syncthreads();
        for (int i = tid; i < CHUNK_ * (C_ / 4); i += 256) {
            int p = i / 24, cq = i - p * 24;
            ushort4 v;
            v.x = tile[4 * cq + 0][p]; v.y = tile[4 * cq + 1][p];
            v.z = tile[4 * cq + 2][p]; v.w = tile[4 * cq + 3][p];
            *((ushort4*)(d + (pl * HW_ + x0 + p) * C_ + 4 * cq)) = v;
        }
    } else {
        __shared__ float tile[C_][CHUNK_ + 1];
        const float* s = (const float*)src;
        float* d = (float*)dst;
        for (int i = tid; i < C_ * (CHUNK_ / 4); i += 256) {
            int ch = i >> 4, xq = i & 15;
            const float4 v = *((const float4*)(s + (pl * C_ + ch) * HW_ + x0 + 4 * xq));
            tile[ch][4 * xq + 0] = v.x; tile[ch][4 * xq + 1] = v.y;
            tile[ch][4 * xq + 2] = v.z; tile[ch][4 * xq + 3] = v.w;
        }
        __syncthreads();
        for (int i = tid; i < CHUNK_ * (C_ / 4); i += 256) {
            int p = i / 24, cq = i - p * 24;
            float4 v;
            v.x = tile[4 * cq + 0][p]; v.y = tile[4 * cq + 1][p];
            v.z = tile[4 * cq + 2][p]; v.w = tile[4 * cq + 3][p];
            *((float4*)(d + (pl * HW_ + x0 + p) * C_ + 4 * cq)) = v;
        }
    }
}

// MODE: 0 = scattered k + scattered cat (no workspace), 1 = transposed k only,
//       2 = transposed k + transposed s1/s2/s3.
// Argmax-critical arithmetic (norm chains, dot chains, strict-> compare) is
// bit-identical to the previously verified kernel in all modes.
template<bool BF16, int MODE>
__global__ __launch_bounds__(256) void traj_main(
    const void* __restrict__ curr, const void* __restrict__ idxf,
    const void* __restrict__ anchor, const void* __restrict__ s1,
    const void* __restrict__ s2, const void* __restrict__ s3,
    const void* __restrict__ loc, const void* __restrict__ pw,
    const void* __restrict__ pb, const void* __restrict__ fw,
    const void* __restrict__ fb, void* __restrict__ outp,
    const int* __restrict__ flag,
    const void* __restrict__ kT, const void* __restrict__ s1T,
    const void* __restrict__ s2T, const void* __restrict__ s3T)
{
    if ((*flag != 0) != BF16) return;

    __shared__ __align__(16) float s_u[P_ * CATP_];   // q [0,1600) | k [1600,3200); cat overlays all
    __shared__ __align__(16) float s_mid[P_][QP_];
    __shared__ int   s_lin[T_][P_];
    __shared__ float s_red[P_][8];
    __shared__ float s_best[P_][HEAD_];
    __shared__ int   s_bidx[P_][HEAD_];
    __shared__ float s_inv[P_];

#define S_Q(pp, ch)  s_u[(pp) * QP_ + (ch)]
#define S_K(pp, ch)  s_u[P_ * QP_ + (pp) * QP_ + (ch)]
#define S_CAT(pp, d) s_u[(pp) * CATP_ + (d)]

    const int tid = threadIdx.x;
    const int b  = blockIdx.x;
    const int nn = b / (HW_ / P_);
    const int p0 = (b - nn * (HW_ / P_)) * P_;

    // ---- nearest-sample indices (mirror reference f32 op sequence exactly) ----
    if (tid < T_ * P_) {
        int t = tid / P_, pp = tid - t * P_;
        int p = p0 + pp;
        float x = ld1<BF16>(loc, (nn * 2 * T_ + 2 * t    ) * HW_ + p);
        float y = ld1<BF16>(loc, (nn * 2 * T_ + 2 * t + 1) * HW_ + p);
        float gx = 2.0f * x / 95.0f - 1.0f;
        float gy = 2.0f * y / 95.0f - 1.0f;
        float fx = (gx + 1.0f) * 0.5f * 95.0f;
        float fy = (gy + 1.0f) * 0.5f * 95.0f;
        float ix = rintf(fx), iy = rintf(fy);     // round-half-even == jnp.round
        bool v = (ix >= 0.0f) && (ix <= 95.0f) && (iy >= 0.0f) && (iy <= 95.0f);
        s_lin[t][pp] = v ? ((int)iy * W_ + (int)ix) : -1;
    }
    if (tid >= 128 && tid < 128 + P_ * HEAD_) {
        int q = tid - 128;
        s_best[q >> 2][q & 3] = -3.0e38f; s_bidx[q >> 2][q & 3] = 0;
    }

    // ---- load curr (float4 along pixels, coalesced) ----
    for (int i = tid; i < C_ * (P_ / 4); i += 256) {
        int ch = i >> 2, pq = i & 3;
        float w[4];
        ld4w<BF16>(curr, (nn * C_ + ch) * HW_ + p0 + 4 * pq, w);
        S_Q(4 * pq + 0, ch) = w[0]; S_Q(4 * pq + 1, ch) = w[1];
        S_Q(4 * pq + 2, ch) = w[2]; S_Q(4 * pq + 3, ch) = w[3];
    }
    __syncthreads();

    // ---- q L2 norm over full c (before head split) ----
    if (tid < P_ * 8) {
        int pp = tid >> 3, j = tid & 7;
        float s = 0.f;
        #pragma unroll
        for (int k = 0; k < 12; ++k) { float v = S_Q(pp, j * 12 + k); s += v * v; }
        s_red[pp][j] = s;
    }
    __syncthreads();
    if (tid < P_) {
        float s = 0.f;
        #pragma unroll
        for (int j = 0; j < 8; ++j) s += s_red[tid][j];
        s_inv[tid] = 1.0f / fmaxf(sqrtf(s), 1e-12f);
    }
    __syncthreads();
    for (int i = tid; i < C_ * P_; i += 256) {
        int pp = i & (P_ - 1), ch = i >> 4;
        S_Q(pp, ch) *= s_inv[pp];
    }

    // ---- per-frame: gather k, normalize, multi-head scores, running argmax ----
    for (int t = 0; t < T_; ++t) {
        __syncthreads();
        if constexpr (MODE >= 1) {
            for (int i = tid; i < 24 * P_; i += 256) {
                int pp = i / 24, j = i - pp * 24;
                int lin = s_lin[t][pp];
                float w[4] = {0.f, 0.f, 0.f, 0.f};
                if (lin >= 0) ld4w<BF16>(kT, ((nn * T_ + t) * HW_ + lin) * C_ + 4 * j, w);
                *((float4*)&S_K(pp, 4 * j)) = make_float4(w[0], w[1], w[2], w[3]);
            }
        } else {
            for (int i = tid; i < C_ * P_; i += 256) {
                int ch = i / P_, pp = i - ch * P_;
                int lin = s_lin[t][pp];
                S_K(pp, ch) = (lin >= 0) ? ld1<BF16>(idxf, ((nn * T_ + t) * C_ + ch) * HW_ + lin) : 0.0f;
            }
        }
        __syncthreads();
        if (tid < P_ * 8) {
            int pp = tid >> 3, j = tid & 7;
            float s = 0.f;
            #pragma unroll
            for (int k = 0; k < 12; ++k) { float v = S_K(pp, j * 12 + k); s += v * v; }
            s_red[pp][j] = s;
        }
        __syncthreads();
        if (tid < P_) {
            float s = 0.f;
            #pragma unroll
            for (int j = 0; j < 8; ++j) s += s_red[tid][j];
            s_inv[tid] = 1.0f / fmaxf(sqrtf(s), 1e-12f);
        }
        __syncthreads();
        if (tid < P_ * HEAD_) {
            int pp = tid >> 2, h = tid & 3;
            float s = 0.f;
            #pragma unroll
            for (int dq = 0; dq < 6; ++dq) {   // same element order as verified scalar chain
                const float4 kv = *((const float4*)&S_K(pp, h * HD_ + 4 * dq));
                const float4 qv = *((const float4*)&S_Q(pp, h * HD_ + 4 * dq));
                s += kv.x * qv.x; s += kv.y * qv.y; s += kv.z * qv.z; s += kv.w * qv.w;
            }
            s *= s_inv[pp];
            if (s > s_best[pp][h]) { s_best[pp][h] = s; s_bidx[pp][h] = t; }  // strict > == first-max
        }
    }
    __syncthreads();

    // ---- gather winning frames from s1/s2/s3 into cat (overlays q/k region) ----
    if constexpr (MODE == 2) {
        for (int i = tid; i < 72 * P_; i += 256) {
            int pp = i / 72, j = i - pp * 72;
            int set = j / 24, jj = j - set * 24;
            int d0 = set * C_ + 4 * jj;
            int bt = s_bidx[pp][jj / 6];
            int lin = s_lin[bt][pp];
            float w[4] = {0.f, 0.f, 0.f, 0.f};
            if (lin >= 0) {
                const void* sp = (set == 0) ? s1T : (set == 1) ? s2T : s3T;
                ld4w<BF16>(sp, ((nn * T_ + bt) * HW_ + lin) * C_ + 4 * jj, w);
            }
            *((float4*)&S_CAT(pp, d0)) = make_float4(w[0], w[1], w[2], w[3]);
        }
    } else {
        for (int i = tid; i < C3_ * P_; i += 256) {
            int pp = i / C3_, d = i - pp * C3_;
            int set = d / C_, ch = d - set * C_;
            int h = ch / HD_;
            int bt = s_bidx[pp][h];
            int lin = s_lin[bt][pp];
            float v = 0.f;
            if (lin >= 0) {
                const void* sp = (set == 0) ? s1 : (set == 1) ? s2 : s3;
                v = ld1<BF16>(sp, ((nn * T_ + bt) * C_ + ch) * HW_ + lin);
            }
            S_CAT(pp, d) = v;
        }
    }
    __syncthreads();

    // ---- fusion GEMV (96 x 288) + bias, scaled by per-head max score ----
    // register-tiled: thread owns 4 co x 4 px -> each 16B weight load feeds 16 FMAs
    if (tid < 96) {
        const int cq = tid >> 2, pq = tid & 3;
        const int co0 = cq * 4, px0 = pq * 4;
        float acc[4][4];
        #pragma unroll
        for (int r = 0; r < 4; ++r)
            #pragma unroll
            for (int k = 0; k < 4; ++k) acc[r][k] = 0.f;
        for (int d = 0; d < C3_; d += 4) {
            float4 cv[4];
            #pragma unroll
            for (int k = 0; k < 4; ++k) cv[k] = *((const float4*)&S_CAT(px0 + k, d));
            #pragma unroll
            for (int r = 0; r < 4; ++r) {
                float w[4]; ld4w<BF16>(fw, (co0 + r) * C3_ + d, w);
                #pragma unroll
                for (int k = 0; k < 4; ++k)
                    acc[r][k] += w[0] * cv[k].x + w[1] * cv[k].y + w[2] * cv[k].z + w[3] * cv[k].w;
            }
        }
        const int hh = co0 / HD_;   // 4 co's never straddle a head (24 % 4 == 0)
        #pragma unroll
        for (int r = 0; r < 4; ++r) {
            float fbv = ld1<BF16>(fb, co0 + r);
            #pragma unroll
            for (int k = 0; k < 4; ++k)
                s_mid[px0 + k][co0 + r] = (acc[r][k] + fbv) * s_best[px0 + k][hh];
        }
    }
    __syncthreads();

    // ---- proj GEMV (96 x 96) + bias + anchor, vectorized store ----
    if (tid < 96) {
        const int dq = tid >> 2, pq = tid & 3;
        const int do0 = dq * 4, px0 = pq * 4;
        float acc[4][4];
        #pragma unroll
        for (int r = 0; r < 4; ++r)
            #pragma unroll
            for (int k = 0; k < 4; ++k) acc[r][k] = 0.f;
        for (int c = 0; c < C_; c += 4) {
            float4 mv[4];
            #pragma unroll
            for (int k = 0; k < 4; ++k) mv[k] = *((const float4*)&s_mid[px0 + k][c]);
            #pragma unroll
            for (int r = 0; r < 4; ++r) {
                float w[4]; ld4w<BF16>(pw, (do0 + r) * C_ + c, w);
                #pragma unroll
                for (int k = 0; k < 4; ++k)
                    acc[r][k] += w[0] * mv[k].x + w[1] * mv[k].y + w[2] * mv[k].z + w[3] * mv[k].w;
            }
        }
        #pragma unroll
        for (int r = 0; r < 4; ++r) {
            float pbv = ld1<BF16>(pb, do0 + r);
            float av[4];
            ld4w<BF16>(anchor, (nn * C_ + do0 + r) * HW_ + p0 + px0, av);
            float res[4];
            #pragma unroll
            for (int k = 0; k < 4; ++k) res[k] = acc[r][k] + pbv + av[k];
            st4w<BF16>(outp, (nn * C_ + do0 + r) * HW_ + p0 + px0, res);
        }
    }
#undef S_Q
#undef S_K
#undef S_CAT
}

extern "C" void kernel_launch(void* const* d_in, const int* in_sizes, int n_in,
                              void* d_out, int out_size, void* d_ws, size_t ws_size,
                              hipStream_t stream) {
    (void)in_sizes; (void)n_in; (void)out_size;
    int* flag = (int*)d_ws;
    char* wsb = (char*)d_ws;
    const unsigned long long SZB = (unsigned long long)N_ * T_ * HW_ * C_ * 4ull; // 49,545,216 (f32 worst case)
    void* kT  = wsb + 512;
    void* s1T = wsb + 512 + SZB;
    void* s2T = wsb + 512 + 2 * SZB;
    void* s3T = wsb + 512 + 3 * SZB;
    const int mode = (ws_size >= 512 + 4 * SZB) ? 2 : (ws_size >= 512 + SZB) ? 1 : 0;

    detect_dtype_kernel<<<1, 64, 0, stream>>>((const u32*)d_in[0], flag);

    if (mode >= 1) {
        dim3 tg(PLANES_ * NCHUNK_, (mode == 2) ? 4 : 1);
        transp_kernel<true ><<<tg, 256, 0, stream>>>(d_in[1], d_in[3], d_in[4], d_in[5], kT, SZB, flag);
        transp_kernel<false><<<tg, 256, 0, stream>>>(d_in[1], d_in[3], d_in[4], d_in[5], kT, SZB, flag);
    }

    dim3 grid(NBLK_), block(256);
#define LAUNCH_MODE(M) \
    traj_main<true,  M><<<grid, block, 0, stream>>>(d_in[0], d_in[1], d_in[2], d_in[3], d_in[4], \
        d_in[5], d_in[6], d_in[7], d_in[8], d_in[9], d_in[10], d_out, flag, kT, s1T, s2T, s3T);  \
    traj_main<false, M><<<grid, block, 0, stream>>>(d_in[0], d_in[1], d_in[2], d_in[3], d_in[4], \
        d_in[5], d_in[6], d_in[7], d_in[8], d_in[9], d_in[10], d_out, flag, kT, s1T, s2T, s3T)

    if (mode == 2)      { LAUNCH_MODE(2); }
    else if (mode == 1) { LAUNCH_MODE(1); }
    else                { LAUNCH_MODE(0); }
#undef LAUNCH_MODE
}

// Round 2
// 332.950 us; speedup vs baseline: 1.0256x; 1.0256x over previous
//
#include <hip/hip_runtime.h>
#include <hip/hip_bf16.h>

#define N_    2
#define T_    7
#define C_    96
#define H_    96
#define W_    96
#define HW_   9216
#define HEAD_ 4
#define HD_   24
#define C3_   288
#define P_    16           // pixels per block: grid 1152, LDS ~26.6KB -> 6 blocks/CU
#define QP_   100          // padded stride for q/k tiles (mult of 4 -> 16B-aligned float4)
#define CATP_ 292          // padded stride for cat tile (mult of 4)
#define NBLK_ (N_ * (HW_ / P_))   // 1152
#define PLANES_ 14         // n*t
#define CHUNK_  64
#define NCHUNK_ 144        // 9216/64

typedef unsigned int u32;

__device__ __forceinline__ float bits2f(u32 b) {
    union { u32 u; float f; } x; x.u = b; return x.f;
}

__device__ __forceinline__ unsigned short f2bf(float f) {
    union { __hip_bfloat16 h; unsigned short s; } u;
    u.h = __float2bfloat16(f);
    return u.s;
}

template<bool BF16>
__device__ __forceinline__ float ld1(const void* p, int i) {
    if constexpr (BF16) return bits2f(((u32)((const unsigned short*)p)[i]) << 16);
    else                return ((const float*)p)[i];
}

// load 4 consecutive elements starting at i (i % 4 == 0)
template<bool BF16>
__device__ __forceinline__ void ld4w(const void* p, int i, float w[4]) {
    if constexpr (BF16) {
        const uint2 u = ((const uint2*)p)[i >> 2];
        w[0] = bits2f(u.x << 16);
        w[1] = bits2f(u.x & 0xFFFF0000u);
        w[2] = bits2f(u.y << 16);
        w[3] = bits2f(u.y & 0xFFFF0000u);
    } else {
        const float4 v = *((const float4*)((const float*)p + i));
        w[0] = v.x; w[1] = v.y; w[2] = v.z; w[3] = v.w;
    }
}

// store 4 consecutive elements starting at i (i % 4 == 0)
template<bool BF16>
__device__ __forceinline__ void st4w(void* p, int i, const float v[4]) {
    if constexpr (BF16) {
        uint2 w;
        w.x = (u32)f2bf(v[0]) | ((u32)f2bf(v[1]) << 16);
        w.y = (u32)f2bf(v[2]) | ((u32)f2bf(v[3]) << 16);
        ((uint2*)p)[i >> 2] = w;
    } else {
        *((float4*)((float*)p + i)) = make_float4(v[0], v[1], v[2], v[3]);
    }
}

// ---- per-block dtype detect: identical decision rule to the verified
// detect_dtype_kernel, computed redundantly by wave 0 of every block.
// Deterministic -> same answer everywhere; removes a kernel launch + the
// flag dependency. curr[0..63] is L2-resident after the first block.
__device__ __forceinline__ bool block_detect_bf16(const u32* __restrict__ w,
                                                  int tid, int* s_flag) {
    if (tid < 64) {
        u32 x = w[tid];
        u32 f = x & 0x7FFFu;
        int inwin = (f >= 0x3A00u) && (f <= 0x4200u);
        unsigned long long m = __ballot(inwin);
        if (tid == 0) *s_flag = (__popcll(m) >= 40) ? 1 : 0;
    }
    __syncthreads();
    return *s_flag != 0;
}

// ---- (c,hw) -> (hw,c) transpose of index_feat only, bit-exact copy ----
template<bool BF16>
__device__ __forceinline__ void transp_body(const void* __restrict__ src,
                                            void* __restrict__ dst,
                                            int bx, int tid, char* tileraw) {
    const int pl = bx / NCHUNK_;
    const int x0 = (bx - pl * NCHUNK_) * CHUNK_;
    if constexpr (BF16) {
        unsigned short (*tile)[CHUNK_ + 2] = (unsigned short (*)[CHUNK_ + 2])tileraw;
        const unsigned short* s = (const unsigned short*)src;
        unsigned short* d = (unsigned short*)dst;
        for (int i = tid; i < C_ * (CHUNK_ / 4); i += 256) {
            int ch = i >> 4, xq = i & 15;
            const ushort4 v = *((const ushort4*)(s + (pl * C_ + ch) * HW_ + x0 + 4 * xq));
            tile[ch][4 * xq + 0] = v.x; tile[ch][4 * xq + 1] = v.y;
            tile[ch][4 * xq + 2] = v.z; tile[ch][4 * xq + 3] = v.w;
        }
        __syncthreads();
        for (int i = tid; i < CHUNK_ * (C_ / 4); i += 256) {
            int p = i / 24, cq = i - p * 24;
            ushort4 v;
            v.x = tile[4 * cq + 0][p]; v.y = tile[4 * cq + 1][p];
            v.z = tile[4 * cq + 2][p]; v.w = tile[4 * cq + 3][p];
            *((ushort4*)(d + (pl * HW_ + x0 + p) * C_ + 4 * cq)) = v;
        }
    } else {
        float (*tile)[CHUNK_ + 1] = (float (*)[CHUNK_ + 1])tileraw;
        const float* s = (const float*)src;
        float* d = (float*)dst;
        for (int i = tid; i < C_ * (CHUNK_ / 4); i += 256) {
            int ch = i >> 4, xq = i & 15;
            const float4 v = *((const float4*)(s + (pl * C_ + ch) * HW_ + x0 + 4 * xq));
            tile[ch][4 * xq + 0] = v.x; tile[ch][4 * xq + 1] = v.y;
            tile[ch][4 * xq + 2] = v.z; tile[ch][4 * xq + 3] = v.w;
        }
        __syncthreads();
        for (int i = tid; i < CHUNK_ * (C_ / 4); i += 256) {
            int p = i / 24, cq = i - p * 24;
            float4 v;
            v.x = tile[4 * cq + 0][p]; v.y = tile[4 * cq + 1][p];
            v.z = tile[4 * cq + 2][p]; v.w = tile[4 * cq + 3][p];
            *((float4*)(d + (pl * HW_ + x0 + p) * C_ + 4 * cq)) = v;
        }
    }
}

__global__ __launch_bounds__(256) void transp_kernel(
    const void* __restrict__ idxf, void* __restrict__ dst,
    const u32* __restrict__ detect_src)
{
    __shared__ __align__(16) char tileraw[C_ * (CHUNK_ + 1) * 4];   // 24.96 KB (f32 worst case)
    __shared__ int s_flag;
    const int tid = threadIdx.x;
    const bool bf = block_detect_bf16(detect_src, tid, &s_flag);
    if (bf) transp_body<true >(idxf, dst, blockIdx.x, tid, tileraw);
    else    transp_body<false>(idxf, dst, blockIdx.x, tid, tileraw);
}

// MODE: 0 = scattered k-gather (no workspace), 1 = k from transposed kT.
// cat gather is scattered (original layout) in both modes -> values and
// all arithmetic bit-identical to the previously verified kernels.
template<bool BF16, int MODE>
__device__ __forceinline__ void traj_body(
    const void* __restrict__ curr, const void* __restrict__ idxf,
    const void* __restrict__ anchor, const void* __restrict__ s1,
    const void* __restrict__ s2, const void* __restrict__ s3,
    const void* __restrict__ loc, const void* __restrict__ pw,
    const void* __restrict__ pb, const void* __restrict__ fw,
    const void* __restrict__ fb, void* __restrict__ outp,
    const void* __restrict__ kT,
    float* s_u, float (*s_mid)[QP_], int (*s_lin)[P_], float (*s_red)[8],
    float (*s_best)[HEAD_], int (*s_bidx)[HEAD_], float* s_inv)
{
#define S_Q(pp, ch)  s_u[(pp) * QP_ + (ch)]
#define S_K(pp, ch)  s_u[P_ * QP_ + (pp) * QP_ + (ch)]
#define S_CAT(pp, d) s_u[(pp) * CATP_ + (d)]

    const int tid = threadIdx.x;
    const int b  = blockIdx.x;
    const int nn = b / (HW_ / P_);
    const int p0 = (b - nn * (HW_ / P_)) * P_;

    // ---- nearest-sample indices (mirror reference f32 op sequence exactly) ----
    if (tid < T_ * P_) {
        int t = tid / P_, pp = tid - t * P_;
        int p = p0 + pp;
        float x = ld1<BF16>(loc, (nn * 2 * T_ + 2 * t    ) * HW_ + p);
        float y = ld1<BF16>(loc, (nn * 2 * T_ + 2 * t + 1) * HW_ + p);
        float gx = 2.0f * x / 95.0f - 1.0f;
        float gy = 2.0f * y / 95.0f - 1.0f;
        float fx = (gx + 1.0f) * 0.5f * 95.0f;
        float fy = (gy + 1.0f) * 0.5f * 95.0f;
        float ix = rintf(fx), iy = rintf(fy);     // round-half-even == jnp.round
        bool v = (ix >= 0.0f) && (ix <= 95.0f) && (iy >= 0.0f) && (iy <= 95.0f);
        s_lin[t][pp] = v ? ((int)iy * W_ + (int)ix) : -1;
    }
    if (tid >= 128 && tid < 128 + P_ * HEAD_) {
        int q = tid - 128;
        s_best[q >> 2][q & 3] = -3.0e38f; s_bidx[q >> 2][q & 3] = 0;
    }

    // ---- load curr (float4 along pixels, coalesced) ----
    for (int i = tid; i < C_ * (P_ / 4); i += 256) {
        int ch = i >> 2, pq = i & 3;
        float w[4];
        ld4w<BF16>(curr, (nn * C_ + ch) * HW_ + p0 + 4 * pq, w);
        S_Q(4 * pq + 0, ch) = w[0]; S_Q(4 * pq + 1, ch) = w[1];
        S_Q(4 * pq + 2, ch) = w[2]; S_Q(4 * pq + 3, ch) = w[3];
    }
    __syncthreads();

    // ---- q L2 norm over full c (before head split) ----
    if (tid < P_ * 8) {
        int pp = tid >> 3, j = tid & 7;
        float s = 0.f;
        #pragma unroll
        for (int k = 0; k < 12; ++k) { float v = S_Q(pp, j * 12 + k); s += v * v; }
        s_red[pp][j] = s;
    }
    __syncthreads();
    if (tid < P_) {
        float s = 0.f;
        #pragma unroll
        for (int j = 0; j < 8; ++j) s += s_red[tid][j];
        s_inv[tid] = 1.0f / fmaxf(sqrtf(s), 1e-12f);
    }
    __syncthreads();
    for (int i = tid; i < C_ * P_; i += 256) {
        int pp = i & (P_ - 1), ch = i >> 4;
        S_Q(pp, ch) *= s_inv[pp];
    }

    // ---- per-frame: gather k, normalize, multi-head scores, running argmax ----
    for (int t = 0; t < T_; ++t) {
        __syncthreads();
        if constexpr (MODE >= 1) {
            for (int i = tid; i < 24 * P_; i += 256) {
                int pp = i / 24, j = i - pp * 24;
                int lin = s_lin[t][pp];
                float w[4] = {0.f, 0.f, 0.f, 0.f};
                if (lin >= 0) ld4w<BF16>(kT, ((nn * T_ + t) * HW_ + lin) * C_ + 4 * j, w);
                *((float4*)&S_K(pp, 4 * j)) = make_float4(w[0], w[1], w[2], w[3]);
            }
        } else {
            for (int i = tid; i < C_ * P_; i += 256) {
                int ch = i / P_, pp = i - ch * P_;
                int lin = s_lin[t][pp];
                S_K(pp, ch) = (lin >= 0) ? ld1<BF16>(idxf, ((nn * T_ + t) * C_ + ch) * HW_ + lin) : 0.0f;
            }
        }
        __syncthreads();
        if (tid < P_ * 8) {
            int pp = tid >> 3, j = tid & 7;
            float s = 0.f;
            #pragma unroll
            for (int k = 0; k < 12; ++k) { float v = S_K(pp, j * 12 + k); s += v * v; }
            s_red[pp][j] = s;
        }
        __syncthreads();
        if (tid < P_) {
            float s = 0.f;
            #pragma unroll
            for (int j = 0; j < 8; ++j) s += s_red[tid][j];
            s_inv[tid] = 1.0f / fmaxf(sqrtf(s), 1e-12f);
        }
        __syncthreads();
        if (tid < P_ * HEAD_) {
            int pp = tid >> 2, h = tid & 3;
            float s = 0.f;
            #pragma unroll
            for (int dq = 0; dq < 6; ++dq) {   // same element order as verified scalar chain
                const float4 kv = *((const float4*)&S_K(pp, h * HD_ + 4 * dq));
                const float4 qv = *((const float4*)&S_Q(pp, h * HD_ + 4 * dq));
                s += kv.x * qv.x; s += kv.y * qv.y; s += kv.z * qv.z; s += kv.w * qv.w;
            }
            s *= s_inv[pp];
            if (s > s_best[pp][h]) { s_best[pp][h] = s; s_bidx[pp][h] = t; }  // strict > == first-max
        }
    }
    __syncthreads();

    // ---- gather winning frames from s1/s2/s3 into cat (scattered, original layout;
    //      values bit-identical to transposed path; line amplification absorbed by L2/L3) ----
    for (int i = tid; i < C3_ * P_; i += 256) {
        int pp = i / C3_, d = i - pp * C3_;
        int set = d / C_, ch = d - set * C_;
        int h = ch / HD_;
        int bt = s_bidx[pp][h];
        int lin = s_lin[bt][pp];
        float v = 0.f;
        if (lin >= 0) {
            const void* sp = (set == 0) ? s1 : (set == 1) ? s2 : s3;
            v = ld1<BF16>(sp, ((nn * T_ + bt) * C_ + ch) * HW_ + lin);
        }
        S_CAT(pp, d) = v;
    }
    __syncthreads();

    // ---- fusion GEMV (96 x 288) + bias, scaled by per-head max score ----
    // register-tiled: thread owns 4 co x 4 px -> each 16B weight load feeds 16 FMAs
    if (tid < 96) {
        const int cq = tid >> 2, pq = tid & 3;
        const int co0 = cq * 4, px0 = pq * 4;
        float acc[4][4];
        #pragma unroll
        for (int r = 0; r < 4; ++r)
            #pragma unroll
            for (int k = 0; k < 4; ++k) acc[r][k] = 0.f;
        for (int d = 0; d < C3_; d += 4) {
            float4 cv[4];
            #pragma unroll
            for (int k = 0; k < 4; ++k) cv[k] = *((const float4*)&S_CAT(px0 + k, d));
            #pragma unroll
            for (int r = 0; r < 4; ++r) {
                float w[4]; ld4w<BF16>(fw, (co0 + r) * C3_ + d, w);
                #pragma unroll
                for (int k = 0; k < 4; ++k)
                    acc[r][k] += w[0] * cv[k].x + w[1] * cv[k].y + w[2] * cv[k].z + w[3] * cv[k].w;
            }
        }
        const int hh = co0 / HD_;   // 4 co's never straddle a head (24 % 4 == 0)
        #pragma unroll
        for (int r = 0; r < 4; ++r) {
            float fbv = ld1<BF16>(fb, co0 + r);
            #pragma unroll
            for (int k = 0; k < 4; ++k)
                s_mid[px0 + k][co0 + r] = (acc[r][k] + fbv) * s_best[px0 + k][hh];
        }
    }
    __syncthreads();

    // ---- proj GEMV (96 x 96) + bias + anchor, vectorized store ----
    if (tid < 96) {
        const int dq = tid >> 2, pq = tid & 3;
        const int do0 = dq * 4, px0 = pq * 4;
        float acc[4][4];
        #pragma unroll
        for (int r = 0; r < 4; ++r)
            #pragma unroll
            for (int k = 0; k < 4; ++k) acc[r][k] = 0.f;
        for (int c = 0; c < C_; c += 4) {
            float4 mv[4];
            #pragma unroll
            for (int k = 0; k < 4; ++k) mv[k] = *((const float4*)&s_mid[px0 + k][c]);
            #pragma unroll
            for (int r = 0; r < 4; ++r) {
                float w[4]; ld4w<BF16>(pw, (do0 + r) * C_ + c, w);
                #pragma unroll
                for (int k = 0; k < 4; ++k)
                    acc[r][k] += w[0] * mv[k].x + w[1] * mv[k].y + w[2] * mv[k].z + w[3] * mv[k].w;
            }
        }
        #pragma unroll
        for (int r = 0; r < 4; ++r) {
            float pbv = ld1<BF16>(pb, do0 + r);
            float av[4];
            ld4w<BF16>(anchor, (nn * C_ + do0 + r) * HW_ + p0 + px0, av);
            float res[4];
            #pragma unroll
            for (int k = 0; k < 4; ++k) res[k] = acc[r][k] + pbv + av[k];
            st4w<BF16>(outp, (nn * C_ + do0 + r) * HW_ + p0 + px0, res);
        }
    }
#undef S_Q
#undef S_K
#undef S_CAT
}

template<int MODE>
__global__ __launch_bounds__(256) void traj_main(
    const void* __restrict__ curr, const void* __restrict__ idxf,
    const void* __restrict__ anchor, const void* __restrict__ s1,
    const void* __restrict__ s2, const void* __restrict__ s3,
    const void* __restrict__ loc, const void* __restrict__ pw,
    const void* __restrict__ pb, const void* __restrict__ fw,
    const void* __restrict__ fb, void* __restrict__ outp,
    const void* __restrict__ kT)
{
    // shared state declared ONCE here and passed to both dtype bodies
    __shared__ __align__(16) float s_u[P_ * CATP_];   // q [0,1600) | k [1600,3200); cat overlays all
    __shared__ __align__(16) float s_mid[P_][QP_];
    __shared__ int   s_lin[T_][P_];
    __shared__ float s_red[P_][8];
    __shared__ float s_best[P_][HEAD_];
    __shared__ int   s_bidx[P_][HEAD_];
    __shared__ float s_inv[P_];
    __shared__ int   s_flag;

    const bool bf = block_detect_bf16((const u32*)curr, threadIdx.x, &s_flag);
    if (bf) traj_body<true,  MODE>(curr, idxf, anchor, s1, s2, s3, loc, pw, pb, fw, fb,
                                   outp, kT, s_u, s_mid, s_lin, s_red, s_best, s_bidx, s_inv);
    else    traj_body<false, MODE>(curr, idxf, anchor, s1, s2, s3, loc, pw, pb, fw, fb,
                                   outp, kT, s_u, s_mid, s_lin, s_red, s_best, s_bidx, s_inv);
}

extern "C" void kernel_launch(void* const* d_in, const int* in_sizes, int n_in,
                              void* d_out, int out_size, void* d_ws, size_t ws_size,
                              hipStream_t stream) {
    (void)in_sizes; (void)n_in; (void)out_size;
    const unsigned long long SZB = (unsigned long long)N_ * T_ * HW_ * C_ * 4ull; // 49,545,216 (f32 worst case)
    void* kT = d_ws;
    const int mode = (ws_size >= SZB) ? 1 : 0;

    dim3 grid(NBLK_), block(256);
    if (mode == 1) {
        transp_kernel<<<dim3(PLANES_ * NCHUNK_), 256, 0, stream>>>(d_in[1], kT, (const u32*)d_in[0]);
        traj_main<1><<<grid, block, 0, stream>>>(d_in[0], d_in[1], d_in[2], d_in[3], d_in[4],
                                                 d_in[5], d_in[6], d_in[7], d_in[8], d_in[9],
                                                 d_in[10], d_out, kT);
    } else {
        traj_main<0><<<grid, block, 0, stream>>>(d_in[0], d_in[1], d_in[2], d_in[3], d_in[4],
                                                 d_in[5], d_in[6], d_in[7], d_in[8], d_in[9],
                                                 d_in[10], d_out, kT);
    }
}